// Round 5
// baseline (64.849 us; speedup 1.0000x reference)
//
#include <hip/hip_runtime.h>

typedef unsigned short u16;
typedef signed char s8;
typedef __attribute__((ext_vector_type(4))) int i32x4;

#define N_PAT 4096
#define KROW  1024            // i8 elements per Y row
#define NMOD  4
#define DDIM  256
#define NTILE 32              // N_PAT / 128
#define NPAIR 528             // NTILE*(NTILE+1)/2
#define KT    16              // K-iterations (BK=64)
#define INV127SQ 6.2000124e-5f  // 1/127^2

// ---------------------------------------------------------------------------
// Kernel 1: prep (blocks 0..4095) + cox (blocks 4096..5119).
// prep: per (m,i) row -> int8 normalized+masked embedding + a/b tables.
// cox: sumexp[i] = sum_j [t_j >= t_i] * exp(h_j); per-block eh in LDS.
// Block 0 also zeroes the gemm completion counter.
// ---------------------------------------------------------------------------
__global__ __launch_bounds__(256) void prep_cox_kernel(
    const float* __restrict__ eb, const float* __restrict__ h,
    const float* __restrict__ t, s8* __restrict__ Yq,
    float* __restrict__ a_tab, float* __restrict__ b_tab,
    float* __restrict__ sumexp, int* __restrict__ ctr)
{
  __shared__ float tl[N_PAT];
  __shared__ float el[N_PAT];
  int tid = threadIdx.x;
  int wid = tid >> 6, lane = tid & 63;

  if (blockIdx.x < 4096) {
    if (blockIdx.x == 0 && tid == 0) *ctr = 0;
    int row = blockIdx.x * 4 + wid;           // row = m*4096 + i
    int m = row >> 12;
    int i = row & (N_PAT - 1);
    const float* base = eb + (size_t)row * DDIM;
    float4 v = *(const float4*)(base + lane * 4);
    float x0 = base[0];
    int eq = (v.x == x0) & (v.y == x0) & (v.z == x0) & (v.w == x0);
    float ss = v.x * v.x + v.y * v.y + v.z * v.z + v.w * v.w;
#pragma unroll
    for (int o = 32; o; o >>= 1) ss += __shfl_xor(ss, o, 64);
    int missing = __all(eq);
    float denom = fmaxf(sqrtf(ss), 1e-8f);
    float inv   = missing ? 0.0f : (127.0f / denom);
    int q0 = __float2int_rn(v.x * inv);
    int q1 = __float2int_rn(v.y * inv);
    int q2 = __float2int_rn(v.z * inv);
    int q3 = __float2int_rn(v.w * inv);
    unsigned int packed = (q0 & 0xFF) | ((q1 & 0xFF) << 8) |
                          ((q2 & 0xFF) << 16) | ((q3 & 0xFF) << 24);
    *(unsigned int*)(Yq + (size_t)i * KROW + m * DDIM + lane * 4) = packed;
    if (lane == 0) {
      float ssim = ss / (denom * denom);      // self-cosine (== ref diagonal)
      a_tab[m * N_PAT + i] = missing ? 0.0f : ssim;
      b_tab[m * N_PAT + i] = missing ? 0.0f : 1.0f;
    }
  } else {
    // ---- cox path ----
    for (int q = tid; q < N_PAT; q += 256) {
      tl[q] = t[q];
      el[q] = expf(h[q]);
    }
    __syncthreads();
    int i = (blockIdx.x - 4096) * 4 + wid;
    float ti = tl[i];
    float s = 0.f;
#pragma unroll
    for (int it = 0; it < 16; ++it) {
      int j = (it * 64 + lane) * 4;
      float4 tv = *(const float4*)(&tl[j]);
      float4 ev = *(const float4*)(&el[j]);
      s += (tv.x >= ti) ? ev.x : 0.f;
      s += (tv.y >= ti) ? ev.y : 0.f;
      s += (tv.z >= ti) ? ev.z : 0.f;
      s += (tv.w >= ti) ? ev.w : 0.f;
    }
#pragma unroll
    for (int o = 32; o; o >>= 1) s += __shfl_xor(s, o, 64);
    if (lane == 0) sumexp[i] = s;
  }
}

// ---------------------------------------------------------------------------
// Kernel 2: triangular 128x128 i8 GEMM tiles (BK=64, ring-2, 32 KB LDS ->
// 4 blocks/CU for cross-block stall soak), fused relu-reduction epilogue,
// last-block deterministic finalize (cox + sum of partials).
// ---------------------------------------------------------------------------
__global__ __launch_bounds__(256) void gemm_sim_kernel(
    const s8* __restrict__ Yq,
    const float* __restrict__ a_tab, const float* __restrict__ b_tab,
    const float* __restrict__ h, const int* __restrict__ ev,
    const float* __restrict__ sumexp, const float* __restrict__ Mp,
    float* __restrict__ partials, int* __restrict__ ctr,
    float* __restrict__ out)
{
  __shared__ s8 Abuf[2][128 * 64];          // 16 KB (aliased as tabs later)
  __shared__ s8 Bbuf[2][128 * 64];          // 16 KB
  __shared__ float redbuf[16];
  __shared__ int lastflag;

  int praw = blockIdx.x;
  int p = (praw & 7) * 66 + (praw >> 3);    // bijective XCD swizzle (528 = 8*66)
  int by = (int)((sqrtf(8.0f * (float)p + 1.0f) - 1.0f) * 0.5f);
  while ((by + 1) * (by + 2) / 2 <= p) ++by;
  while (by * (by + 1) / 2 > p) --by;
  int bx = p - by * (by + 1) / 2;           // bx <= by
  int brow = bx * 128, bcol = by * 128;

  int tid  = threadIdx.x;
  int lane = tid & 63;
  int wid  = tid >> 6;
  int wr = wid >> 1, wc = wid & 1;

  // Stage A/B 128x64 i8 tiles for K-iter tt into ring slot pb.
  // LDS dest linear in chunk index q (rule #21); source chunk XOR-swizzled
  // cs = c ^ ((r>>1)&3)  -> frag reads at same XOR are 2-way (free).
#define STAGE(tt, pb)                                                          \
  {                                                                            \
    _Pragma("unroll")                                                          \
    for (int h_ = 0; h_ < 2; ++h_) {                                           \
      int q_ = tid + h_ * 256;              /* 512 chunks of 16B per matrix */ \
      int r_ = q_ >> 2, c_ = q_ & 3;                                           \
      int cs_ = c_ ^ ((r_ >> 1) & 3);                                          \
      const s8* sA_ = Yq + (size_t)(brow + r_) * KROW + (tt) * 64 + cs_ * 16;  \
      const s8* sB_ = Yq + (size_t)(bcol + r_) * KROW + (tt) * 64 + cs_ * 16;  \
      __builtin_amdgcn_global_load_lds(                                        \
          (const __attribute__((address_space(1))) void*)sA_,                  \
          (__attribute__((address_space(3))) void*)(&Abuf[pb][q_ * 16]),       \
          16, 0, 0);                                                           \
      __builtin_amdgcn_global_load_lds(                                        \
          (const __attribute__((address_space(1))) void*)sB_,                  \
          (__attribute__((address_space(3))) void*)(&Bbuf[pb][q_ * 16]),       \
          16, 0, 0);                                                           \
    }                                                                          \
  }

  STAGE(0, 0);
  asm volatile("s_waitcnt vmcnt(0)" ::: "memory");
  __builtin_amdgcn_s_barrier();

  const i32x4 zero = {0, 0, 0, 0};
  i32x4 acc[4][4];
#pragma unroll
  for (int a = 0; a < 4; ++a)
#pragma unroll
    for (int b = 0; b < 4; ++b) acc[a][b] = zero;

  for (int t = 0; t < KT; ++t) {
    int pb = t & 1;
    if (t + 1 < KT) STAGE(t + 1, pb ^ 1);   // issue next-tile loads FIRST

    i32x4 af[4], bf[4];
    int g = lane >> 4;
#pragma unroll
    for (int mi = 0; mi < 4; ++mi) {
      int r = wr * 64 + mi * 16 + (lane & 15);
      int c = g ^ ((r >> 1) & 3);
      af[mi] = *(const i32x4*)(&Abuf[pb][r * 64 + c * 16]);
    }
#pragma unroll
    for (int ni = 0; ni < 4; ++ni) {
      int r = wc * 64 + ni * 16 + (lane & 15);
      int c = g ^ ((r >> 1) & 3);
      bf[ni] = *(const i32x4*)(&Bbuf[pb][r * 64 + c * 16]);
    }
    __builtin_amdgcn_s_setprio(1);
#pragma unroll
    for (int mi = 0; mi < 4; ++mi)
#pragma unroll
      for (int ni = 0; ni < 4; ++ni)
        acc[mi][ni] = __builtin_amdgcn_mfma_i32_16x16x64_i8(
            af[mi], bf[ni], acc[mi][ni], 0, 0, 0);
    __builtin_amdgcn_s_setprio(0);
    asm volatile("s_waitcnt vmcnt(0)" ::: "memory");  // next tile landed
    __builtin_amdgcn_s_barrier();
  }
#undef STAGE

  // ---- epilogue: a/b tables into LDS (reuse Abuf), fused relu-reduction ----
  float* tabs = (float*)&Abuf[0][0];        // [4][NMOD][128] = 8 KB
  for (int q = tid; q < 4 * NMOD * 128; q += 256) {
    int tb = q >> 9;                        // 0=aR 1=bR 2=aC 3=bC
    int m  = (q >> 7) & 3;
    int i  = q & 127;
    int base = (tb & 2) ? bcol : brow;
    const float* srct = (tb & 1) ? b_tab : a_tab;
    tabs[(tb * NMOD + m) * 128 + i] = srct[m * N_PAT + base + i];
  }
  __syncthreads();

  float Mv = Mp[0];
  float lsum = 0.0f;
  bool offd = (bx != by);
#pragma unroll
  for (int mi = 0; mi < 4; ++mi) {
#pragma unroll
    for (int ni = 0; ni < 4; ++ni) {
#pragma unroll
      for (int j = 0; j < 4; ++j) {
        int il = wr * 64 + mi * 16 + ((lane >> 4) << 2) + j;  // C row (local)
        int jl = wc * 64 + ni * 16 + (lane & 15);             // C col (local)
        float msim = (float)acc[mi][ni][j] * INV127SQ;
        float p1 = 0.f;
#pragma unroll
        for (int m = 0; m < NMOD; ++m)
          p1 += tabs[(0 * NMOD + m) * 128 + il] * tabs[(3 * NMOD + m) * 128 + jl];
        float t1 = Mv - msim + p1;
        if ((brow + il) != (bcol + jl) && t1 > 0.f) lsum += t1;
        if (offd) {
          float p2 = 0.f;
#pragma unroll
          for (int m = 0; m < NMOD; ++m)
            p2 += tabs[(2 * NMOD + m) * 128 + jl] * tabs[(1 * NMOD + m) * 128 + il];
          float t2 = Mv - msim + p2;
          if (t2 > 0.f) lsum += t2;
        }
      }
    }
  }
#pragma unroll
  for (int o = 32; o; o >>= 1) lsum += __shfl_xor(lsum, o, 64);
  if (lane == 0) redbuf[wid] = lsum;
  __syncthreads();
  if (tid == 0) {
    float s = redbuf[0] + redbuf[1] + redbuf[2] + redbuf[3];
    __hip_atomic_store(&partials[p], s, __ATOMIC_RELAXED,
                       __HIP_MEMORY_SCOPE_AGENT);
    int prev = __hip_atomic_fetch_add(ctr, 1, __ATOMIC_ACQ_REL,
                                      __HIP_MEMORY_SCOPE_AGENT);
    lastflag = (prev == NPAIR - 1);
  }
  __syncthreads();

  // ---- last block: deterministic finalize (cox + ordered partials sum) ----
  if (lastflag) {
    float num = 0.f, den = 0.f, sim = 0.f;
    for (int i = tid; i < N_PAT; i += 256) {
      float e = (float)ev[i];
      num += e * (h[i] - logf(sumexp[i]));
      den += e;
    }
    // fixed per-thread assignment + fixed-order tree: deterministic
    {
      float v = __hip_atomic_load(&partials[tid], __ATOMIC_RELAXED,
                                  __HIP_MEMORY_SCOPE_AGENT);
      float w = __hip_atomic_load(&partials[tid + 256], __ATOMIC_RELAXED,
                                  __HIP_MEMORY_SCOPE_AGENT);
      sim = v + w;
      if (tid < NPAIR - 512)
        sim += __hip_atomic_load(&partials[tid + 512], __ATOMIC_RELAXED,
                                 __HIP_MEMORY_SCOPE_AGENT);
    }
#pragma unroll
    for (int o = 32; o; o >>= 1) {
      num += __shfl_xor(num, o, 64);
      den += __shfl_xor(den, o, 64);
      sim += __shfl_xor(sim, o, 64);
    }
    if (lane == 0) {
      redbuf[wid] = num; redbuf[4 + wid] = den; redbuf[8 + wid] = sim;
    }
    __syncthreads();
    if (tid == 0) {
      float n = redbuf[0] + redbuf[1] + redbuf[2] + redbuf[3];
      float d = redbuf[4] + redbuf[5] + redbuf[6] + redbuf[7];
      float s = redbuf[8] + redbuf[9] + redbuf[10] + redbuf[11];
      out[0] = -n / d + s;
    }
  }
}

// ---------------------------------------------------------------------------
extern "C" void kernel_launch(void* const* d_in, const int* in_sizes, int n_in,
                              void* d_out, int out_size, void* d_ws, size_t ws_size,
                              hipStream_t stream)
{
  const float* h  = (const float*)d_in[0];
  const float* eb = (const float*)d_in[1];
  const float* tm = (const float*)d_in[2];
  const int*   ev = (const int*)d_in[3];
  const float* Mp = (const float*)d_in[4];
  float* out = (float*)d_out;

  char* ws = (char*)d_ws;
  s8*    Yq       = (s8*)ws;                                    // 4 MB
  float* a_tab    = (float*)(ws + (size_t)4 * 1024 * 1024);     // 64 KB
  float* b_tab    = a_tab + NMOD * N_PAT;                       // 64 KB
  float* sumexp   = b_tab + NMOD * N_PAT;                       // 16 KB
  float* partials = sumexp + N_PAT;                             // 768 floats (pad)
  int*   ctr      = (int*)(partials + 768);

  prep_cox_kernel<<<dim3(5120), dim3(256), 0, stream>>>(
      eb, h, tm, Yq, a_tab, b_tab, sumexp, ctr);
  gemm_sim_kernel<<<dim3(NPAIR), dim3(256), 0, stream>>>(
      Yq, a_tab, b_tab, h, ev, sumexp, Mp, partials, ctr, out);
}